// Round 6
// baseline (944.091 us; speedup 1.0000x reference)
//
#include <hip/hip_runtime.h>
#include <hip/hip_bf16.h>
#include <cstdint>

// Problem constants
#define SDIM   2048
#define DDIM   1024
#define VDIM   50257
#define VPAD   50432          // 197 * 256
#define NROWS  4094           // B*(S-1) = 2*2047
#define MPAD   4096
#define NTM    16             // M tiles of 256
#define NTN    197            // N tiles of 256
#define NCHUNK (NTN * 4)      // 788 column chunks of 64
#define NKT    16             // 1024 / 64
#define IGNORE_IDX (-100)
// Finite "minus infinity": avoids exp(-inf - -inf) = NaN on all-padding chunks.
#define NEGBIG (-3.0e38f)
#define SLICE_SH 8192         // one K-slice: 256 rows x 32 cols bf16 = 16KB

typedef __bf16 bf16x8 __attribute__((ext_vector_type(8)));
typedef float  f32x4  __attribute__((ext_vector_type(4)));

__device__ static inline unsigned short f2bf(float f) {
    union { float f; uint32_t u; } v; v.f = f;
    uint32_t u = v.u;
    return (unsigned short)((u + 0x7FFFu + ((u >> 16) & 1u)) >> 16);  // RNE
}

// global -> LDS direct (16B per lane). LDS dest must be wave-uniform base + lane*16.
__device__ static inline void gload_lds16(const void* g, void* l) {
    __builtin_amdgcn_global_load_lds(
        (const __attribute__((address_space(1))) unsigned int*)(g),
        (__attribute__((address_space(3))) unsigned int*)(l),
        16, 0, 0);
}

// ---------------- convert W (fp32 [V,D]) -> bf16 [VPAD,D], pad rows zero ----
__global__ __launch_bounds__(256) void k_convert_W(const float* __restrict__ W,
                                                   unsigned short* __restrict__ Wb,
                                                   float* __restrict__ acc) {
    if (blockIdx.x == 0 && threadIdx.x < 2) acc[threadIdx.x] = 0.f;  // zero accumulators
    const int nf4 = VPAD * (DDIM / 4);
    for (int i = blockIdx.x * 256 + threadIdx.x; i < nf4; i += gridDim.x * 256) {
        const int row = i >> 8;               // 256 float4 per row
        const int c4  = (i & 255) << 2;
        ushort4 o;
        if (row < VDIM) {
            const float4 f = *(const float4*)(W + (size_t)row * DDIM + c4);
            o.x = f2bf(f.x); o.y = f2bf(f.y); o.z = f2bf(f.z); o.w = f2bf(f.w);
        } else {
            o.x = o.y = o.z = o.w = 0;
        }
        *(ushort4*)(Wb + (size_t)row * DDIM + c4) = o;
    }
}

// --------- pack shifted embeddings: row r<4094 -> emb[b= r/2047, s= r%2047] ---
__global__ __launch_bounds__(256) void k_convert_A(const float* __restrict__ emb,
                                                   unsigned short* __restrict__ Ab) {
    const int nf4 = MPAD * (DDIM / 4);
    for (int i = blockIdx.x * 256 + threadIdx.x; i < nf4; i += gridDim.x * 256) {
        const int row = i >> 8;
        const int c4  = (i & 255) << 2;
        ushort4 o; o.x = o.y = o.z = o.w = 0;
        if (row < NROWS) {
            const int bb = row / 2047;
            const int s  = row - bb * 2047;
            const float4 f = *(const float4*)(emb + ((size_t)bb * SDIM + s) * DDIM + c4);
            o.x = f2bf(f.x); o.y = f2bf(f.y); o.z = f2bf(f.z); o.w = f2bf(f.w);
        }
        *(ushort4*)(Ab + (size_t)row * DDIM + c4) = o;
    }
}

// ---------------- GEMM 256x256 tile, BK=64, 8 waves, counted-vmcnt pipeline --
// LDS: per matrix, [2 bufs][2 K-slices][256 rows][32 cols] bf16.
// Slice physical layout: [128 lines][8 chunks(16B)]; chunk p at line L holds
// row = 2L + (p>>2), col-slot cs = (p&3) ^ (L&3)  (cs = 8 bf16 cols).
// global_load_lds writes linearly; the global SOURCE applies the same XOR
// involution (rule 21); reads apply it too. Max 2-way bank aliasing (free).
// Pipeline per K-tile t (computing buf c, staging t+1 into buf c^1):
//   P1: stage s0(t+1); vmcnt(8); barrier; ds(mh0,ks0); lgkm; MFMA
//   P2:                                   ds(mh1,ks0); lgkm; MFMA
//   P3: stage s1(t+1); vmcnt(8); barrier; ds(mh0,ks1); lgkm; MFMA
//   P4:                                   ds(mh1,ks1); lgkm; barrier; MFMA
// vmcnt(8) retires exactly the slice needed this phase (issued 4 phases ago);
// 8 loads (2 slices) always stay in flight. Tail tile: vmcnt(4) then vmcnt(0).
__global__ __launch_bounds__(512, 2) void k_gemm(const unsigned short* __restrict__ Ab,
                                                 const unsigned short* __restrict__ Wb,
                                                 const float* __restrict__ bias,
                                                 float2* __restrict__ Pml) {
    extern __shared__ unsigned short lds[];        // 128 KiB dynamic
    unsigned short* As = lds;                      // [2][2][SLICE_SH]
    unsigned short* Bs = lds + 4 * SLICE_SH;       // [2][2][SLICE_SH]

    const int tid  = threadIdx.x;
    const int wave = tid >> 6, lane = tid & 63;
    const int q    = lane & 15, g = lane >> 4;
    const int wr   = wave >> 2;        // 0..1  (M half: 128 rows)
    const int wc   = wave & 3;         // 0..3  (N quarter: 64 cols)

    // Bijective XCD swizzle: nwg = 16*197 = 3152, 3152 % 8 == 0.
    const int bid0 = (int)blockIdx.x;
    const int bid  = (bid0 & 7) * (NTM * NTN / 8) + (bid0 >> 3);
    const int tm   = bid & 15;         // M fastest: consecutive blocks share W panel
    const int tn   = bid >> 4;
    const size_t arow0 = (size_t)tm * 256;
    const size_t brow0 = (size_t)tn * 256;

    f32x4 acc[8][4];
    const f32x4 zf = {0.f, 0.f, 0.f, 0.f};
#pragma unroll
    for (int i = 0; i < 8; ++i)
#pragma unroll
        for (int j = 0; j < 4; ++j) acc[i][j] = zf;

    // stage one K-slice (A and B) of tile kt into buffer bufIdx: 4 instr/wave.
    auto stage_slice = [&](int bufIdx, int kt, int s) {
        unsigned short* LA = As + (bufIdx * 2 + s) * SLICE_SH;
        unsigned short* LB = Bs + (bufIdx * 2 + s) * SLICE_SH;
#pragma unroll
        for (int j = 0; j < 2; ++j) {
            const int ci  = j * 512 + tid;                 // this lane's 16B chunk
            const int row = ((ci >> 3) << 1) + ((ci >> 2) & 1);
            const int cs  = (ci & 3) ^ ((ci >> 3) & 3);    // pre-swizzled source slot
            const size_t goff = (size_t)kt * 64 + s * 32 + cs * 8;
            unsigned short* ldst = (unsigned short*)((size_t)(j * 512 + wave * 64) * 8);
            gload_lds16(Ab + (arow0 + row) * DDIM + goff, LA + (size_t)(j * 512 + wave * 64) * 8);
            gload_lds16(Wb + (brow0 + row) * DDIM + goff, LB + (size_t)(j * 512 + wave * 64) * 8);
            (void)ldst;
        }
    };

    // read one MFMA fragment (row, k-chunk g) from slice base SL
    auto lds_frag = [&](const unsigned short* SL, int row) -> bf16x8 {
        const int line = row >> 1;
        const int p    = ((row & 1) << 2) + (g ^ (line & 3));
        return *(const bf16x8*)(SL + line * 64 + p * 8);
    };

    // one phase: optional stage+wait+barrier, ds-read quadrant, MFMA cluster
    auto do_phase = [&](int c, int mh, int ks, int stageT, int vm, bool tileEndBar) {
        if (stageT >= 0) stage_slice(c ^ 1, stageT, ks);
        if (vm == 8)      { asm volatile("s_waitcnt vmcnt(8)" ::: "memory"); }
        else if (vm == 4) { asm volatile("s_waitcnt vmcnt(4)" ::: "memory"); }
        else if (vm == 0) { asm volatile("s_waitcnt vmcnt(0)" ::: "memory"); }
        if (vm >= 0) {
            __builtin_amdgcn_sched_barrier(0);
            __builtin_amdgcn_s_barrier();
        }
        const unsigned short* SA = As + (c * 2 + ks) * SLICE_SH;
        const unsigned short* SB = Bs + (c * 2 + ks) * SLICE_SH;
        bf16x8 af[4], bfr[4];
#pragma unroll
        for (int fi = 0; fi < 4; ++fi)
            af[fi] = lds_frag(SA, wr * 128 + mh * 64 + fi * 16 + q);
#pragma unroll
        for (int fj = 0; fj < 4; ++fj)
            bfr[fj] = lds_frag(SB, wc * 64 + fj * 16 + q);
        asm volatile("s_waitcnt lgkmcnt(0)" ::: "memory");
        __builtin_amdgcn_sched_barrier(0);
        if (tileEndBar) __builtin_amdgcn_s_barrier();
        __builtin_amdgcn_s_setprio(1);
#pragma unroll
        for (int fi = 0; fi < 4; ++fi)
#pragma unroll
            for (int fj = 0; fj < 4; ++fj)
                acc[mh * 4 + fi][fj] = __builtin_amdgcn_mfma_f32_16x16x32_bf16(
                    af[fi], bfr[fj], acc[mh * 4 + fi][fj], 0, 0, 0);
        __builtin_amdgcn_s_setprio(0);
        __builtin_amdgcn_sched_barrier(0);
    };

    // prologue: stage both slices of tile 0 into buf 0 (8 loads in flight)
    stage_slice(0, 0, 0);
    stage_slice(0, 0, 1);

#pragma unroll 1
    for (int t = 0; t < NKT - 1; ++t) {
        const int c = t & 1;
        do_phase(c, 0, 0, t + 1, 8, false);   // P1: stage s0(t+1), wait slice s0(t)
        do_phase(c, 1, 0, -1, -1, false);     // P2
        do_phase(c, 0, 1, t + 1, 8, false);   // P3: stage s1(t+1), wait slice s1(t)
        do_phase(c, 1, 1, -1, -1, true);      // P4: tile-boundary barrier
    }
    {   // tail tile t = NKT-1, c = (NKT-1)&1
        const int c = (NKT - 1) & 1;
        do_phase(c, 0, 0, -1, 4, false);      // wait s0 (4 newer loads allowed)
        do_phase(c, 1, 0, -1, -1, false);
        do_phase(c, 0, 1, -1, 0, false);      // wait s1 (drain)
        do_phase(c, 1, 1, -1, -1, false);     // no boundary barrier needed
    }

    // -------- epilogue: per-row partial (max, sumexp) over this wave's 64 cols
    float bv[4]; int colv[4];
#pragma unroll
    for (int fj = 0; fj < 4; ++fj) {
        const int col = tn * 256 + wc * 64 + fj * 16 + q;
        colv[fj] = col;
        bv[fj] = (col < VDIM) ? bias[col] : 0.f;
    }
#pragma unroll
    for (int mf = 0; mf < 8; ++mf) {
#pragma unroll
        for (int r = 0; r < 4; ++r) {
            float vv[4];
#pragma unroll
            for (int fj = 0; fj < 4; ++fj) {
                const float lv = acc[mf][fj][r] + bv[fj];
                vv[fj] = (colv[fj] < VDIM) ? lv : NEGBIG;
            }
            float m = fmaxf(fmaxf(vv[0], vv[1]), fmaxf(vv[2], vv[3]));
#pragma unroll
            for (int mask = 1; mask < 16; mask <<= 1) m = fmaxf(m, __shfl_xor(m, mask));
            // all-pad chunk: m == NEGBIG, vv-m == 0, s harmless (zeroed in combine)
            float s = __expf(vv[0] - m) + __expf(vv[1] - m) +
                      __expf(vv[2] - m) + __expf(vv[3] - m);
#pragma unroll
            for (int mask = 1; mask < 16; mask <<= 1) s += __shfl_xor(s, mask);
            if (q == ((mf * 4 + r) & 15)) {
                const int rowg = tm * 256 + wr * 128 + mf * 16 + g * 4 + r;
                Pml[(size_t)rowg * NCHUNK + (tn * 4 + wc)] = make_float2(m, s);
            }
        }
    }
}

// ---------------- finalize: per row, combine partials + label logit ---------
__global__ __launch_bounds__(256) void k_finalize(const float2* __restrict__ Pml,
                                                  const float* __restrict__ emb,
                                                  const float* __restrict__ W,
                                                  const float* __restrict__ bias,
                                                  const int* __restrict__ labels,
                                                  float* __restrict__ acc) {
    const int r    = blockIdx.x;          // 0..NROWS-1
    const int tid  = threadIdx.x;
    const int lane = tid & 63, wave = tid >> 6;

    float m = NEGBIG, l = 0.f;
    for (int c = tid; c < NCHUNK; c += 256) {
        const float2 p = Pml[(size_t)r * NCHUNK + c];
        const float mn = fmaxf(m, p.x);
        l = l * __expf(m - mn) + p.y * __expf(p.x - mn);
        m = mn;
    }
#pragma unroll
    for (int mask = 1; mask < 64; mask <<= 1) {
        const float om = __shfl_xor(m, mask);
        const float ol = __shfl_xor(l, mask);
        const float mn = fmaxf(m, om);
        l = l * __expf(m - mn) + ol * __expf(om - mn);
        m = mn;
    }

    // label logit: fp32 dot(emb_row, W[label]) + bias[label]
    const int bb = r / 2047;
    const int s  = r - bb * 2047;
    const int label = labels[bb * SDIM + s + 1];
    const bool valid = (label != IGNORE_IDX);
    const int lab = valid ? label : 0;
    const float* erow = emb + ((size_t)bb * SDIM + s) * DDIM;
    const float* wrow = W + (size_t)lab * DDIM;
    const float4 e  = *(const float4*)(erow + tid * 4);
    const float4 w4 = *(const float4*)(wrow + tid * 4);
    float d = e.x * w4.x + e.y * w4.y + e.z * w4.z + e.w * w4.w;
#pragma unroll
    for (int mask = 1; mask < 64; mask <<= 1) d += __shfl_xor(d, mask);

    __shared__ float sm[4], sl[4], sd[4];
    if (lane == 0) { sm[wave] = m; sl[wave] = l; sd[wave] = d; }
    __syncthreads();
    if (tid == 0) {
        float M = sm[0], L = sl[0];
#pragma unroll
        for (int wv = 1; wv < 4; ++wv) {
            const float mn = fmaxf(M, sm[wv]);
            L = L * __expf(M - mn) + sl[wv] * __expf(sm[wv] - mn);
            M = mn;
        }
        const float dot = sd[0] + sd[1] + sd[2] + sd[3];
        const float lse = M + logf(L);
        const float logit = dot + bias[lab];
        const float ce = valid ? (lse - logit) : 0.f;
        const float pt = __expf(-ce);
        const float w  = valid ? (1.f - pt) : 0.f;   // gamma = 1.0
        atomicAdd(acc + 0, w * ce);
        atomicAdd(acc + 1, w);
    }
}

__global__ void k_final(const float* __restrict__ acc, float* __restrict__ out) {
    out[0] = acc[0] / acc[1];
}

extern "C" void kernel_launch(void* const* d_in, const int* in_sizes, int n_in,
                              void* d_out, int out_size, void* d_ws, size_t ws_size,
                              hipStream_t stream) {
    const float* emb    = (const float*)d_in[0];
    const float* W      = (const float*)d_in[1];
    const float* bias   = (const float*)d_in[2];
    const int*   labels = (const int*)d_in[3];
    // d_in[4] (input_ids) unused

    char* ws = (char*)d_ws;
    const size_t WB = (size_t)VPAD * DDIM * 2;       // 103,284,736
    const size_t AB = (size_t)MPAD * DDIM * 2;       //   8,388,608
    const size_t PB = (size_t)MPAD * NCHUNK * 8;     //  25,821,184
    unsigned short* Wb  = (unsigned short*)ws;
    unsigned short* Ab  = (unsigned short*)(ws + WB);
    float2*         Pml = (float2*)(ws + WB + AB);
    float*          acc = (float*)(ws + WB + AB + PB);

    k_convert_W<<<2048, 256, 0, stream>>>(W, Wb, acc);
    k_convert_A<<<1024, 256, 0, stream>>>(emb, Ab);
    k_gemm<<<NTM * NTN, 512, 131072, stream>>>(Ab, Wb, bias, Pml);
    k_finalize<<<NROWS, 256, 0, stream>>>(Pml, emb, W, bias, labels, acc);
    k_final<<<1, 1, 0, stream>>>(acc, (float*)d_out);
}